// Round 2
// baseline (355.004 us; speedup 1.0000x reference)
//
#include <hip/hip_runtime.h>
#include <hip/hip_bf16.h>
#include <math.h>

// Problem constants
#define N_ROUTES 7
#define PC_DIM   512
#define MC_DIM   128
#define KCLS     25
#define BATCH    4096

#define ROW_IN   (N_ROUTES * PC_DIM)          // 3584 elems per batch row of pose
#define JDIM     (KCLS * MC_DIM)              // 3200 vote cols per route
#define VOTE_B   (N_ROUTES * JDIM)            // 22400 vote elems per batch elem

typedef __attribute__((ext_vector_type(8))) _Float16 half8;
typedef __attribute__((ext_vector_type(4))) float f32x4;

__device__ inline ushort f2h(float f) {
    _Float16 h = (_Float16)f;
    return __builtin_bit_cast(ushort, h);
}

__device__ inline float2 h2f2(uint u) {
    union { uint x; _Float16 h[2]; } c; c.x = u;
    return make_float2((float)c.h[0], (float)c.h[1]);
}

__device__ inline void load_lds16(const void* g, void* l) {
    __builtin_amdgcn_global_load_lds(
        (const __attribute__((address_space(1))) void*)g,
        (__attribute__((address_space(3))) void*)l, 16, 0, 0);
}

// ---------------- conversion kernels ----------------
__global__ __launch_bounds__(256) void conv_pose(const float* __restrict__ p,
                                                 ushort* __restrict__ pb, int n8) {
    int i = blockIdx.x * 256 + threadIdx.x;
    if (i >= n8) return;
    const float4* s = (const float4*)p + (size_t)i * 2;
    float4 a = s[0], b = s[1];
    ushort t[8];
    t[0]=f2h(a.x); t[1]=f2h(a.y); t[2]=f2h(a.z); t[3]=f2h(a.w);
    t[4]=f2h(b.x); t[5]=f2h(b.y); t[6]=f2h(b.z); t[7]=f2h(b.w);
    *(uint4*)(pb + (size_t)i * 8) = *(uint4*)t;
}

// w fp32 [7][512][3200] -> wt fp16 [7][3200][512] (transposed per route)
__global__ __launch_bounds__(256) void conv_w(const float* __restrict__ w,
                                              ushort* __restrict__ wt) {
    __shared__ float t[32][33];
    const int j0 = blockIdx.x * 32, d0 = blockIdx.y * 32, r = blockIdx.z;
    const int c = threadIdx.x & 31, rr = threadIdx.x >> 5;
    const float* wp = w + (size_t)r * PC_DIM * JDIM;
#pragma unroll
    for (int i = 0; i < 4; i++)
        t[rr + i * 8][c] = wp[(size_t)(d0 + rr + i * 8) * JDIM + j0 + c];
    __syncthreads();
    ushort* op = wt + (size_t)r * JDIM * PC_DIM;
#pragma unroll
    for (int i = 0; i < 4; i++)
        op[(size_t)(j0 + rr + i * 8) * PC_DIM + d0 + c] = f2h(t[c][rr + i * 8]);
}

// ---------------- Kernel 1: MFMA vote GEMM (fp16 in, fp16 out) ----------------
// r9: 128x128 tile (BN=128 -> N=3200 exact, no padding), BK=32, 256 threads
// (4 waves, 2Mx2N, wave tile 64x64, acc[4][4] = 64 AGPR). 3-deep LDS rotation
// (3 x 16KB = 48KB) -> 3 blocks/CU: independent blocks overlap each other's
// LDS bursts and MFMA bursts (the additive-phase fix r8's 1-block/CU design
// could not have). Counted vmcnt: stage tile t+2 at top of tile t, wait
// vmcnt(4) (= tile t+1 landed) at tile end -- never 0 in steady state.
// setprio(1) around the 16-MFMA cluster. XOR swizzle (verified r8 math):
// chunk c ^ ((row>>1)&3), linear LDS dest + pre-swizzled global source.

#define BAR() do { __builtin_amdgcn_sched_barrier(0); \
                   __builtin_amdgcn_s_barrier(); \
                   __builtin_amdgcn_sched_barrier(0); } while (0)
#define WAIT_LGKM0() do { asm volatile("s_waitcnt lgkmcnt(0)" ::: "memory"); \
                          __builtin_amdgcn_sched_barrier(0); } while (0)
#define WAIT_VM(n) do { asm volatile("s_waitcnt vmcnt(" #n ")" ::: "memory"); } while (0)

__global__ __launch_bounds__(256, 3) void vote_gemm_mfma(
        const ushort* __restrict__ poseb,  // [rows][3584] fp16 (chunk-offset)
        const ushort* __restrict__ wt,     // [7][3200][512] fp16
        ushort* __restrict__ vote,         // [rows][7][3200] fp16 (chunk-local)
        int rows) {
    __shared__ __align__(16) char smem[49152];   // 3 bufs x (A 8KB | B 8KB)

    // Grid = nRowTiles * 175 (175 = 7 routes x 25 jTiles).
    int route, rowTile, jTile;
    {
        const int blk = blockIdx.x;
        const int nrt = gridDim.x / 175;
        if ((nrt & 7) == 0) {              // XCD swizzle: per-XCD contiguous rowTiles
            const int per = nrt >> 3;
            const int x = blk & 7;         // XCD id (perf heuristic only)
            const int g = blk >> 3;
            const int q = g / 175;
            const int rem = g - q * 175;
            route = rem / 25;
            jTile = rem - route * 25;
            rowTile = x * per + q;
        } else {
            rowTile = blk / 175;
            const int rem = blk - rowTile * 175;
            route = rem / 25;
            jTile = rem - route * 25;
        }
    }
    const int b0 = rowTile * 128;
    const int j0 = jTile * 128;

    const int tid = threadIdx.x;
    const int l = tid & 63, w = tid >> 6;
    const int wm = w >> 1, wn = w & 1;     // 2 M-waves x 2 N-waves
    const int lm = l & 15, q4 = l >> 4;
    const int xr = (l >> 1) & 3;           // == ((row>>1)&3) for row = 16k + lm

    const ushort* Aptr = poseb + (size_t)route * PC_DIM;
    const ushort* Bptr = wt + (size_t)route * JDIM * PC_DIM;

    // Staging source offsets (elements). 512 chunks of 8 fp16 per operand tile;
    // chunk f: row = f>>2, c = f&3, pre-swizzled source col-group qg = c^((row>>1)&3).
    uint aof0, aof1, bof0, bof1;
    {
        int f, row, c, qg, ga;
        f = tid;        row = f >> 2; c = f & 3; qg = c ^ ((row >> 1) & 3);
        ga = b0 + row; if (ga >= rows) ga = rows - 1;
        aof0 = (uint)ga * ROW_IN + qg * 8;
        bof0 = (uint)(j0 + row) * PC_DIM + qg * 8;      // j0+row <= 3199 always
        f = tid + 256;  row = f >> 2; c = f & 3; qg = c ^ ((row >> 1) & 3);
        ga = b0 + row; if (ga >= rows) ga = rows - 1;
        aof1 = (uint)ga * ROW_IN + qg * 8;
        bof1 = (uint)(j0 + row) * PC_DIM + qg * 8;
    }

    // LDS byte offsets of this lane's fragments (swizzled read side).
    // A section at buf+0, B at buf+8192; row addr = (row*4 + pos)*16.
    const int aBase = ((wm * 64 + lm) * 4 + (q4 ^ xr)) * 16;           // + mt*1024
    const int bBase = 8192 + ((wn * 64 + lm) * 4 + (q4 ^ xr)) * 16;    // + nt*1024

    f32x4 acc[4][4] = {};

#define STAGE(kt) do { \
        char* d_ = smem + (((kt) % 3) * 16384); \
        load_lds16(Aptr + aof0 + (kt) * 32, d_ + (size_t)tid * 16); \
        load_lds16(Aptr + aof1 + (kt) * 32, d_ + (size_t)(tid + 256) * 16); \
        load_lds16(Bptr + bof0 + (kt) * 32, d_ + 8192 + (size_t)tid * 16); \
        load_lds16(Bptr + bof1 + (kt) * 32, d_ + 8192 + (size_t)(tid + 256) * 16); \
    } while (0)

    // Prologue: tiles 0,1 staged (8 loads/thread); wait tile0 (leave 4).
    STAGE(0); STAGE(1);
    WAIT_VM(4);
    BAR();

    half8 af[4], bf[4];

#pragma unroll
    for (int t = 0; t < 16; ++t) {
        if (t < 14) STAGE(t + 2);          // issue-early: loads in flight across tile
        const char* bp_ = smem + ((t % 3) * 16384);
#pragma unroll
        for (int nt = 0; nt < 4; nt++)
            bf[nt] = *(const half8*)(bp_ + bBase + nt * 1024);
#pragma unroll
        for (int mt = 0; mt < 4; mt++)
            af[mt] = *(const half8*)(bp_ + aBase + mt * 1024);
        WAIT_LGKM0();
        __builtin_amdgcn_s_setprio(1);
#pragma unroll
        for (int mt = 0; mt < 4; mt++)
#pragma unroll
            for (int nt = 0; nt < 4; nt++)
                acc[mt][nt] = __builtin_amdgcn_mfma_f32_16x16x32_f16(
                    af[mt], bf[nt], acc[mt][nt], 0, 0, 0);
        __builtin_amdgcn_s_setprio(0);
        if (t < 14)       WAIT_VM(4);      // tile t+1 landed; t+2 still in flight
        else if (t == 14) WAIT_VM(0);      // drain: tile 15 landed
        BAR();                             // also protects epilogue smem reuse (t=15)
    }

    // Epilogue: per-wave LDS transpose (wave-private 16x68 region, lgkm-fenced).
    float* ep = (float*)smem + w * 1088;   // 16*68 floats per wave
    const int erow = l >> 2, ec0 = (l & 3) * 16;
#pragma unroll
    for (int mt = 0; mt < 4; mt++) {
#pragma unroll
        for (int nt = 0; nt < 4; nt++)
#pragma unroll
            for (int i = 0; i < 4; i++)
                ep[(q4 * 4 + i) * 68 + nt * 16 + lm] = acc[mt][nt][i];
        asm volatile("s_waitcnt lgkmcnt(0)" ::: "memory");
        const int grow = b0 + wm * 64 + mt * 16 + erow;
        if (grow < rows) {
            ushort t16[16];
#pragma unroll
            for (int t8 = 0; t8 < 4; t8++) {
                float4 v = *(float4*)&ep[erow * 68 + ec0 + t8 * 4];
                t16[t8*4+0]=f2h(v.x); t16[t8*4+1]=f2h(v.y);
                t16[t8*4+2]=f2h(v.z); t16[t8*4+3]=f2h(v.w);
            }
            ushort* dst = vote + (size_t)grow * VOTE_B + route * JDIM + j0 + wn * 64 + ec0;
            ((uint4*)dst)[0] = ((uint4*)t16)[0];
            ((uint4*)dst)[1] = ((uint4*)t16)[1];
        }
        asm volatile("s_waitcnt lgkmcnt(0)" ::: "memory");
    }
}

// ---------------- Kernel 2: fused routing ----------------
// Block = one batch elem, 448 threads (7 waves). Lane decomposition:
//   sub = l&15 -> v-dims [8*sub, 8*sub+8);  mg = l>>4;  m = wv + 7*mg (28 slots, 25 valid).
// Votes unpacked ONCE to 56 fp32 regs. Reductions: 4-step shfl over 16 lanes.
__global__ __launch_bounds__(448) void routing_kernel(
        const ushort* __restrict__ vote16,  // [chunk][7][25][128] fp16
        const float* __restrict__ act,      // (pre-offset)
        const float* __restrict__ gamma,
        const float* __restrict__ beta,
        const float* __restrict__ emb,      // [25,128]
        const float* __restrict__ bias,     // [25]
        float* __restrict__ out_logits,
        float* __restrict__ out_act,
        float* __restrict__ out_coef) {
    const int b = blockIdx.x;
    __shared__ float coef_s[N_ROUTES * KCLS];
    __shared__ float act_s[8];

    const int tid = threadIdx.x, l = tid & 63, wv = tid >> 6;   // 7 waves
    const int sub = l & 15, mg = l >> 4;
    const int m = wv + 7 * mg;                // 0..27
    const bool mv = (m < KCLS);

    if (tid < N_ROUTES) {
        float a = act[(size_t)b * N_ROUTES + tid];
        act_s[tid] = a;
        out_act[(size_t)b * N_ROUTES + tid] = a;
    }

    // Load votes (coalesced 16B) and unpack to fp32 ONCE.
    float vf[N_ROUTES][8];
    if (mv) {
        const uint4* vb = (const uint4*)(vote16 + (size_t)b * VOTE_B);  // n*400 + m*16 + sub
#pragma unroll
        for (int n = 0; n < N_ROUTES; n++) {
            uint4 q = vb[n * 400 + m * 16 + sub];
            float2 f0 = h2f2(q.x), f1 = h2f2(q.y), f2 = h2f2(q.z), f3 = h2f2(q.w);
            vf[n][0] = f0.x; vf[n][1] = f0.y; vf[n][2] = f1.x; vf[n][3] = f1.y;
            vf[n][4] = f2.x; vf[n][5] = f2.y; vf[n][6] = f3.x; vf[n][7] = f3.y;
        }
    } else {
#pragma unroll
        for (int n = 0; n < N_ROUTES; n++)
#pragma unroll
            for (int j = 0; j < 8; j++) vf[n][j] = 0.f;
    }
    const int mc = mv ? m : 24;

    float g[8], be[8];
    *(float4*)(g)      = *(const float4*)(gamma + 8 * sub);
    *(float4*)(g + 4)  = *(const float4*)(gamma + 8 * sub + 4);
    *(float4*)(be)     = *(const float4*)(beta  + 8 * sub);
    *(float4*)(be + 4) = *(const float4*)(beta  + 8 * sub + 4);
    __syncthreads();   // act_s ready

    const float scale = 0.088388347648318447f;    // 1/sqrt(128)
    float pose[8];

    auto update = [&](bool first) {
        float r[8];
#pragma unroll
        for (int j = 0; j < 8; j++) r[j] = 0.f;
#pragma unroll
        for (int n = 0; n < N_ROUTES; n++) {
            float c = first ? (act_s[n] * 0.04f) : (coef_s[n * KCLS + mc] * act_s[n]);
#pragma unroll
            for (int j = 0; j < 8; j++) r[j] += c * vf[n][j];
        }
        float S = 0.f, Q = 0.f;
#pragma unroll
        for (int j = 0; j < 8; j++) { S += r[j]; Q += r[j] * r[j]; }
#pragma unroll
        for (int o = 8; o; o >>= 1) {
            S += __shfl_xor(S, o);
            Q += __shfl_xor(Q, o);
        }
        float mean = S * 0.0078125f;
        float var  = Q * 0.0078125f - mean * mean;
        float rs   = rsqrtf(var + 1e-5f);
#pragma unroll
        for (int j = 0; j < 8; j++) pose[j] = (r[j] - mean) * rs * g[j] + be[j];
    };

    update(true);
    __syncthreads();

    const int sgrp = tid >> 5, slane = tid & 31;   // 14 x 32-lane groups for softmax

    for (int it = 1; it < 3; it++) {
        // agreement: d[n] = <vote[n][m], pose[m]>
        float d[N_ROUTES];
#pragma unroll
        for (int n = 0; n < N_ROUTES; n++) {
            float t = 0.f;
#pragma unroll
            for (int j = 0; j < 8; j++) t += vf[n][j] * pose[j];
            d[n] = t;
        }
#pragma unroll
        for (int o = 8; o; o >>= 1)
#pragma unroll
            for (int n = 0; n < N_ROUTES; n++) d[n] += __shfl_xor(d[n], o);
        if (sub == 0 && mv) {
#pragma unroll
            for (int n = 0; n < N_ROUTES; n++) coef_s[n * KCLS + m] = d[n] * scale;
        }
        __syncthreads();
        // parallel softmax: group sgrp = route, lane slane = m
        if (sgrp < N_ROUTES) {
            float c = (slane < KCLS) ? coef_s[sgrp * KCLS + slane] : -1e30f;
            float mx = c;
#pragma unroll
            for (int o = 16; o; o >>= 1) mx = fmaxf(mx, __shfl_xor(mx, o, 32));
            float e = (slane < KCLS) ? expf(c - mx) : 0.f;
            float s = e;
#pragma unroll
            for (int o = 16; o; o >>= 1) s += __shfl_xor(s, o, 32);
            if (slane < KCLS) coef_s[sgrp * KCLS + slane] = e / s;
        }
        __syncthreads();
        update(false);
        if (it == 1) __syncthreads();   // coef_s reads done before next agree overwrites
    }

    // logits
    float e[8];
    *(float4*)(e)     = *(const float4*)(emb + mc * MC_DIM + 8 * sub);
    *(float4*)(e + 4) = *(const float4*)(emb + mc * MC_DIM + 8 * sub + 4);
    float dd = 0.f;
#pragma unroll
    for (int j = 0; j < 8; j++) dd += pose[j] * e[j];
#pragma unroll
    for (int o = 8; o; o >>= 1) dd += __shfl_xor(dd, o);
    if (sub == 0 && mv) out_logits[(size_t)b * KCLS + m] = dd + bias[m];

    if (tid < N_ROUTES * KCLS)
        out_coef[(size_t)b * (N_ROUTES * KCLS) + tid] = coef_s[tid];
}

// ---------------- launch ----------------
extern "C" void kernel_launch(void* const* d_in, const int* in_sizes, int n_in,
                              void* d_out, int out_size, void* d_ws, size_t ws_size,
                              hipStream_t stream) {
    const float* pose  = (const float*)d_in[0];
    const float* act   = (const float*)d_in[1];
    const float* w     = (const float*)d_in[2];
    const float* gamma = (const float*)d_in[3];
    const float* beta  = (const float*)d_in[4];
    const float* emb   = (const float*)d_in[5];
    const float* bias  = (const float*)d_in[6];

    float* out        = (float*)d_out;
    float* out_logits = out;
    float* out_act    = out + BATCH * KCLS;
    float* out_coef   = out + BATCH * KCLS + BATCH * N_ROUTES;

    // workspace: wt fp16 | poseb fp16 | vote fp16 (chunked)
    const size_t wt_bytes    = (size_t)N_ROUTES * JDIM * PC_DIM * 2;
    const size_t poseb_bytes = (size_t)BATCH * ROW_IN * 2;
    ushort* wt    = (ushort*)d_ws;
    ushort* poseb = (ushort*)((char*)d_ws + wt_bytes);
    ushort* voteh = (ushort*)((char*)d_ws + wt_bytes + poseb_bytes);

    size_t rem = ws_size > wt_bytes + poseb_bytes ? ws_size - wt_bytes - poseb_bytes : 0;
    size_t cap = rem / ((size_t)VOTE_B * 2);
    // chunk = 2048: vote chunk (91.8 MB) + wt (22.9) + poseb chunk (14.7) stays
    // L3-resident -> B never evicted by the vote stream; vote lines get
    // overwritten in-cache next chunk (only the last flush hits HBM); routing
    // reads votes L3-hot.
    int chunk;
    if (cap >= 2048)      chunk = 2048;
    else if (cap >= 128)  chunk = (int)(cap & ~(size_t)127);
    else                  chunk = (int)(cap > 0 ? cap : 1);

    conv_w<<<dim3(JDIM / 32, PC_DIM / 32, N_ROUTES), 256, 0, stream>>>(w, wt);
    const int n8 = BATCH * ROW_IN / 8;
    conv_pose<<<(n8 + 255) / 256, 256, 0, stream>>>(pose, poseb, n8);

    for (int b0 = 0; b0 < BATCH; b0 += chunk) {
        int rows = BATCH - b0 < chunk ? BATCH - b0 : chunk;
        int nRowTiles = (rows + 127) / 128;
        vote_gemm_mfma<<<nRowTiles * 175, 256, 0, stream>>>(
            poseb + (size_t)b0 * ROW_IN, wt, voteh, rows);
        routing_kernel<<<rows, 448, 0, stream>>>(
            voteh,
            act + (size_t)b0 * N_ROUTES,
            gamma, beta, emb, bias,
            out_logits + (size_t)b0 * KCLS,
            out_act    + (size_t)b0 * N_ROUTES,
            out_coef   + (size_t)b0 * N_ROUTES * KCLS);
    }
}

// Round 3
// 335.542 us; speedup vs baseline: 1.0580x; 1.0580x over previous
//
#include <hip/hip_runtime.h>
#include <hip/hip_bf16.h>
#include <math.h>

// Problem constants
#define N_ROUTES 7
#define PC_DIM   512
#define MC_DIM   128
#define KCLS     25
#define BATCH    4096

#define ROW_IN   (N_ROUTES * PC_DIM)          // 3584 elems per batch row of pose
#define JDIM     (KCLS * MC_DIM)              // 3200 vote cols per route
#define VOTE_B   (N_ROUTES * JDIM)            // 22400 vote elems per batch elem

typedef __attribute__((ext_vector_type(8))) _Float16 half8;
typedef __attribute__((ext_vector_type(4))) float f32x4;

__device__ inline ushort f2h(float f) {
    _Float16 h = (_Float16)f;
    return __builtin_bit_cast(ushort, h);
}

__device__ inline float2 h2f2(uint u) {
    union { uint x; _Float16 h[2]; } c; c.x = u;
    return make_float2((float)c.h[0], (float)c.h[1]);
}

__device__ inline void load_lds16(const void* g, void* l) {
    __builtin_amdgcn_global_load_lds(
        (const __attribute__((address_space(1))) void*)g,
        (__attribute__((address_space(3))) void*)l, 16, 0, 0);
}

// ---------------- conversion kernels ----------------
__global__ __launch_bounds__(256) void conv_pose(const float* __restrict__ p,
                                                 ushort* __restrict__ pb, int n8) {
    int i = blockIdx.x * 256 + threadIdx.x;
    if (i >= n8) return;
    const float4* s = (const float4*)p + (size_t)i * 2;
    float4 a = s[0], b = s[1];
    ushort t[8];
    t[0]=f2h(a.x); t[1]=f2h(a.y); t[2]=f2h(a.z); t[3]=f2h(a.w);
    t[4]=f2h(b.x); t[5]=f2h(b.y); t[6]=f2h(b.z); t[7]=f2h(b.w);
    *(uint4*)(pb + (size_t)i * 8) = *(uint4*)t;
}

// w fp32 [7][512][3200] -> wt fp16 [7][3200][512] (transposed per route).
// r10: 32j x 64d tile so each output j-row is written as a FULL 128B line
// (8 threads x uint4) -- the old 64B half-line writes caused write-allocate
// RMW traffic. LDS stride 65 floats: store bank = (j + d) mod 32, conflict-free.
__global__ __launch_bounds__(256) void conv_w(const float* __restrict__ w,
                                              ushort* __restrict__ wt) {
    __shared__ float t[32][65];
    const int j0 = blockIdx.x * 32, d0 = blockIdx.y * 64, r = blockIdx.z;
    const int jc = threadIdx.x & 31, dr0 = threadIdx.x >> 5;   // 8 d-rows/pass
    const float* wp = w + (size_t)r * PC_DIM * JDIM;
#pragma unroll
    for (int i = 0; i < 8; i++)
        t[jc][dr0 + i * 8] = wp[(size_t)(d0 + dr0 + i * 8) * JDIM + j0 + jc];
    __syncthreads();
    const int jr = threadIdx.x >> 3, dc = (threadIdx.x & 7) * 8;
    ushort o[8];
#pragma unroll
    for (int k = 0; k < 8; k++) o[k] = f2h(t[jr][dc + k]);
    ushort* op = wt + (size_t)r * JDIM * PC_DIM;
    *(uint4*)(op + (size_t)(j0 + jr) * PC_DIM + d0 + dc) = *(uint4*)o;
}

// ---------------- Kernel 1: MFMA vote GEMM (fp16 in, fp16 out) ----------------
// r10 = r9 pipeline + r7 block->XCD mapping (the FETCH-verified one).
// 128x128 tile, BK=32, 256 threads (4 waves 2Mx2N, wave tile 64x64, acc 64 AGPR).
// 3-deep LDS rotation (48KB -> 3 blocks/CU); counted vmcnt: stage t+2 at top of
// tile t, wait vmcnt(4) at tile end (tile t+1 landed, t+2 in flight) -- never 0
// in steady state. setprio(1) around the 16-MFMA cluster. XOR swizzle:
// chunk c ^ ((row>>1)&3), linear LDS dest + pre-swizzled global source.
// Mapping (r7, FETCH 161MB): per XCD ~28 consecutive (route,rowTile) codes,
// jTile innermost -> per-XCD B working set ~ one route's panel (3.27MB ~ L2).

#define BAR() do { __builtin_amdgcn_sched_barrier(0); \
                   __builtin_amdgcn_s_barrier(); \
                   __builtin_amdgcn_sched_barrier(0); } while (0)
#define WAIT_LGKM0() do { asm volatile("s_waitcnt lgkmcnt(0)" ::: "memory"); \
                          __builtin_amdgcn_sched_barrier(0); } while (0)
#define WAIT_VM(n) do { asm volatile("s_waitcnt vmcnt(" #n ")" ::: "memory"); } while (0)

__global__ __launch_bounds__(256, 3) void vote_gemm_mfma(
        const ushort* __restrict__ poseb,  // [rows][3584] fp16
        const ushort* __restrict__ wt,     // [7][3200][512] fp16
        ushort* __restrict__ vote,         // [rows][7][3200] fp16
        int rows) {
    __shared__ __align__(16) char smem[49152];   // 3 bufs x (A 8KB | B 8KB)

    int route, rowTile, jTile;
    {
        const int blk = blockIdx.x;
        if (gridDim.x == 5600) {           // full batch: 32 rowTiles x 7 x 25
            const int x = blk & 7;         // XCD id (perf heuristic only)
            const int g = blk >> 3;        // 0..699
            const int q = g / 25;          // 0..27
            jTile = g - q * 25;
            const int p = x * 28 + q;      // 0..223 = route*32 + rowTile
            route = p >> 5;
            rowTile = p & 31;
        } else {
            rowTile = blk / 175;
            const int rem = blk - rowTile * 175;
            route = rem / 25;
            jTile = rem - route * 25;
        }
    }
    const int b0 = rowTile * 128;
    const int j0 = jTile * 128;

    const int tid = threadIdx.x;
    const int l = tid & 63, w = tid >> 6;
    const int wm = w >> 1, wn = w & 1;     // 2 M-waves x 2 N-waves
    const int lm = l & 15, q4 = l >> 4;
    const int xr = (l >> 1) & 3;           // == ((row>>1)&3) for row = 16k + lm

    const ushort* Aptr = poseb + (size_t)route * PC_DIM;
    const ushort* Bptr = wt + (size_t)route * JDIM * PC_DIM;

    // Staging source offsets (elements). 512 chunks of 8 fp16 per operand tile;
    // chunk f: row = f>>2, c = f&3, pre-swizzled source col-group qg = c^((row>>1)&3).
    uint aof0, aof1, bof0, bof1;
    {
        int f, row, c, qg, ga;
        f = tid;        row = f >> 2; c = f & 3; qg = c ^ ((row >> 1) & 3);
        ga = b0 + row; if (ga >= rows) ga = rows - 1;
        aof0 = (uint)ga * ROW_IN + qg * 8;
        bof0 = (uint)(j0 + row) * PC_DIM + qg * 8;      // j0+row <= 3199 always
        f = tid + 256;  row = f >> 2; c = f & 3; qg = c ^ ((row >> 1) & 3);
        ga = b0 + row; if (ga >= rows) ga = rows - 1;
        aof1 = (uint)ga * ROW_IN + qg * 8;
        bof1 = (uint)(j0 + row) * PC_DIM + qg * 8;
    }

    // LDS byte offsets of this lane's fragments (swizzled read side).
    // A section at buf+0, B at buf+8192; row addr = (row*4 + pos)*16.
    const int aBase = ((wm * 64 + lm) * 4 + (q4 ^ xr)) * 16;           // + mt*1024
    const int bBase = 8192 + ((wn * 64 + lm) * 4 + (q4 ^ xr)) * 16;    // + nt*1024

    f32x4 acc[4][4] = {};

#define STAGE(kt) do { \
        char* d_ = smem + (((kt) % 3) * 16384); \
        load_lds16(Aptr + aof0 + (kt) * 32, d_ + (size_t)tid * 16); \
        load_lds16(Aptr + aof1 + (kt) * 32, d_ + (size_t)(tid + 256) * 16); \
        load_lds16(Bptr + bof0 + (kt) * 32, d_ + 8192 + (size_t)tid * 16); \
        load_lds16(Bptr + bof1 + (kt) * 32, d_ + 8192 + (size_t)(tid + 256) * 16); \
    } while (0)

    // Prologue: tiles 0,1 staged (8 loads/thread); wait tile0 (leave 4).
    STAGE(0); STAGE(1);
    WAIT_VM(4);
    BAR();

    half8 af[4], bf[4];

#pragma unroll
    for (int t = 0; t < 16; ++t) {
        if (t < 14) STAGE(t + 2);          // issue-early: loads in flight across tile
        const char* bp_ = smem + ((t % 3) * 16384);
#pragma unroll
        for (int nt = 0; nt < 4; nt++)
            bf[nt] = *(const half8*)(bp_ + bBase + nt * 1024);
#pragma unroll
        for (int mt = 0; mt < 4; mt++)
            af[mt] = *(const half8*)(bp_ + aBase + mt * 1024);
        WAIT_LGKM0();
        __builtin_amdgcn_s_setprio(1);
#pragma unroll
        for (int mt = 0; mt < 4; mt++)
#pragma unroll
            for (int nt = 0; nt < 4; nt++)
                acc[mt][nt] = __builtin_amdgcn_mfma_f32_16x16x32_f16(
                    af[mt], bf[nt], acc[mt][nt], 0, 0, 0);
        __builtin_amdgcn_s_setprio(0);
        if (t < 14)       WAIT_VM(4);      // tile t+1 landed; t+2 still in flight
        else if (t == 14) WAIT_VM(0);      // drain: tile 15 landed
        BAR();                             // also protects epilogue smem reuse (t=15)
    }

    // Epilogue: per-wave LDS transpose (wave-private 16x68 region, lgkm-fenced).
    float* ep = (float*)smem + w * 1088;   // 16*68 floats per wave
    const int erow = l >> 2, ec0 = (l & 3) * 16;
#pragma unroll
    for (int mt = 0; mt < 4; mt++) {
#pragma unroll
        for (int nt = 0; nt < 4; nt++)
#pragma unroll
            for (int i = 0; i < 4; i++)
                ep[(q4 * 4 + i) * 68 + nt * 16 + lm] = acc[mt][nt][i];
        asm volatile("s_waitcnt lgkmcnt(0)" ::: "memory");
        const int grow = b0 + wm * 64 + mt * 16 + erow;
        if (grow < rows) {
            ushort t16[16];
#pragma unroll
            for (int t8 = 0; t8 < 4; t8++) {
                float4 v = *(float4*)&ep[erow * 68 + ec0 + t8 * 4];
                t16[t8*4+0]=f2h(v.x); t16[t8*4+1]=f2h(v.y);
                t16[t8*4+2]=f2h(v.z); t16[t8*4+3]=f2h(v.w);
            }
            ushort* dst = vote + (size_t)grow * VOTE_B + route * JDIM + j0 + wn * 64 + ec0;
            ((uint4*)dst)[0] = ((uint4*)t16)[0];
            ((uint4*)dst)[1] = ((uint4*)t16)[1];
        }
        asm volatile("s_waitcnt lgkmcnt(0)" ::: "memory");
    }
}

// ---------------- Kernel 2: fused routing ----------------
// Block = one batch elem, 448 threads (7 waves). Lane decomposition:
//   sub = l&15 -> v-dims [8*sub, 8*sub+8);  mg = l>>4;  m = wv + 7*mg (28 slots, 25 valid).
// Votes unpacked ONCE to 56 fp32 regs. Reductions: 4-step shfl over 16 lanes.
__global__ __launch_bounds__(448) void routing_kernel(
        const ushort* __restrict__ vote16,  // [chunk][7][25][128] fp16
        const float* __restrict__ act,      // (pre-offset)
        const float* __restrict__ gamma,
        const float* __restrict__ beta,
        const float* __restrict__ emb,      // [25,128]
        const float* __restrict__ bias,     // [25]
        float* __restrict__ out_logits,
        float* __restrict__ out_act,
        float* __restrict__ out_coef) {
    const int b = blockIdx.x;
    __shared__ float coef_s[N_ROUTES * KCLS];
    __shared__ float act_s[8];

    const int tid = threadIdx.x, l = tid & 63, wv = tid >> 6;   // 7 waves
    const int sub = l & 15, mg = l >> 4;
    const int m = wv + 7 * mg;                // 0..27
    const bool mv = (m < KCLS);

    if (tid < N_ROUTES) {
        float a = act[(size_t)b * N_ROUTES + tid];
        act_s[tid] = a;
        out_act[(size_t)b * N_ROUTES + tid] = a;
    }

    // Load votes (coalesced 16B) and unpack to fp32 ONCE.
    float vf[N_ROUTES][8];
    if (mv) {
        const uint4* vb = (const uint4*)(vote16 + (size_t)b * VOTE_B);  // n*400 + m*16 + sub
#pragma unroll
        for (int n = 0; n < N_ROUTES; n++) {
            uint4 q = vb[n * 400 + m * 16 + sub];
            float2 f0 = h2f2(q.x), f1 = h2f2(q.y), f2 = h2f2(q.z), f3 = h2f2(q.w);
            vf[n][0] = f0.x; vf[n][1] = f0.y; vf[n][2] = f1.x; vf[n][3] = f1.y;
            vf[n][4] = f2.x; vf[n][5] = f2.y; vf[n][6] = f3.x; vf[n][7] = f3.y;
        }
    } else {
#pragma unroll
        for (int n = 0; n < N_ROUTES; n++)
#pragma unroll
            for (int j = 0; j < 8; j++) vf[n][j] = 0.f;
    }
    const int mc = mv ? m : 24;

    float g[8], be[8];
    *(float4*)(g)      = *(const float4*)(gamma + 8 * sub);
    *(float4*)(g + 4)  = *(const float4*)(gamma + 8 * sub + 4);
    *(float4*)(be)     = *(const float4*)(beta  + 8 * sub);
    *(float4*)(be + 4) = *(const float4*)(beta  + 8 * sub + 4);
    __syncthreads();   // act_s ready

    const float scale = 0.088388347648318447f;    // 1/sqrt(128)
    float pose[8];

    auto update = [&](bool first) {
        float r[8];
#pragma unroll
        for (int j = 0; j < 8; j++) r[j] = 0.f;
#pragma unroll
        for (int n = 0; n < N_ROUTES; n++) {
            float c = first ? (act_s[n] * 0.04f) : (coef_s[n * KCLS + mc] * act_s[n]);
#pragma unroll
            for (int j = 0; j < 8; j++) r[j] += c * vf[n][j];
        }
        float S = 0.f, Q = 0.f;
#pragma unroll
        for (int j = 0; j < 8; j++) { S += r[j]; Q += r[j] * r[j]; }
#pragma unroll
        for (int o = 8; o; o >>= 1) {
            S += __shfl_xor(S, o);
            Q += __shfl_xor(Q, o);
        }
        float mean = S * 0.0078125f;
        float var  = Q * 0.0078125f - mean * mean;
        float rs   = rsqrtf(var + 1e-5f);
#pragma unroll
        for (int j = 0; j < 8; j++) pose[j] = (r[j] - mean) * rs * g[j] + be[j];
    };

    update(true);
    __syncthreads();

    const int sgrp = tid >> 5, slane = tid & 31;   // 14 x 32-lane groups for softmax

    for (int it = 1; it < 3; it++) {
        // agreement: d[n] = <vote[n][m], pose[m]>
        float d[N_ROUTES];
#pragma unroll
        for (int n = 0; n < N_ROUTES; n++) {
            float t = 0.f;
#pragma unroll
            for (int j = 0; j < 8; j++) t += vf[n][j] * pose[j];
            d[n] = t;
        }
#pragma unroll
        for (int o = 8; o; o >>= 1)
#pragma unroll
            for (int n = 0; n < N_ROUTES; n++) d[n] += __shfl_xor(d[n], o);
        if (sub == 0 && mv) {
#pragma unroll
            for (int n = 0; n < N_ROUTES; n++) coef_s[n * KCLS + m] = d[n] * scale;
        }
        __syncthreads();
        // parallel softmax: group sgrp = route, lane slane = m
        if (sgrp < N_ROUTES) {
            float c = (slane < KCLS) ? coef_s[sgrp * KCLS + slane] : -1e30f;
            float mx = c;
#pragma unroll
            for (int o = 16; o; o >>= 1) mx = fmaxf(mx, __shfl_xor(mx, o, 32));
            float e = (slane < KCLS) ? expf(c - mx) : 0.f;
            float s = e;
#pragma unroll
            for (int o = 16; o; o >>= 1) s += __shfl_xor(s, o, 32);
            if (slane < KCLS) coef_s[sgrp * KCLS + slane] = e / s;
        }
        __syncthreads();
        update(false);
        if (it == 1) __syncthreads();   // coef_s reads done before next agree overwrites
    }

    // logits
    float e[8];
    *(float4*)(e)     = *(const float4*)(emb + mc * MC_DIM + 8 * sub);
    *(float4*)(e + 4) = *(const float4*)(emb + mc * MC_DIM + 8 * sub + 4);
    float dd = 0.f;
#pragma unroll
    for (int j = 0; j < 8; j++) dd += pose[j] * e[j];
#pragma unroll
    for (int o = 8; o; o >>= 1) dd += __shfl_xor(dd, o);
    if (sub == 0 && mv) out_logits[(size_t)b * KCLS + m] = dd + bias[m];

    if (tid < N_ROUTES * KCLS)
        out_coef[(size_t)b * (N_ROUTES * KCLS) + tid] = coef_s[tid];
}

// ---------------- launch ----------------
extern "C" void kernel_launch(void* const* d_in, const int* in_sizes, int n_in,
                              void* d_out, int out_size, void* d_ws, size_t ws_size,
                              hipStream_t stream) {
    const float* pose  = (const float*)d_in[0];
    const float* act   = (const float*)d_in[1];
    const float* w     = (const float*)d_in[2];
    const float* gamma = (const float*)d_in[3];
    const float* beta  = (const float*)d_in[4];
    const float* emb   = (const float*)d_in[5];
    const float* bias  = (const float*)d_in[6];

    float* out        = (float*)d_out;
    float* out_logits = out;
    float* out_act    = out + BATCH * KCLS;
    float* out_coef   = out + BATCH * KCLS + BATCH * N_ROUTES;

    // workspace: wt fp16 | poseb fp16 | vote fp16 (chunked)
    const size_t wt_bytes    = (size_t)N_ROUTES * JDIM * PC_DIM * 2;
    const size_t poseb_bytes = (size_t)BATCH * ROW_IN * 2;
    ushort* wt    = (ushort*)d_ws;
    ushort* poseb = (ushort*)((char*)d_ws + wt_bytes);
    ushort* voteh = (ushort*)((char*)d_ws + wt_bytes + poseb_bytes);

    size_t rem = ws_size > wt_bytes + poseb_bytes ? ws_size - wt_bytes - poseb_bytes : 0;
    size_t cap = rem / ((size_t)VOTE_B * 2);
    int chunk;
    if (cap >= (size_t)BATCH)  chunk = BATCH;   // single dispatch: deepest grid, no tail split
    else if (cap >= 128)       chunk = (int)(cap & ~(size_t)127);
    else                       chunk = (int)(cap > 0 ? cap : 1);

    conv_w<<<dim3(JDIM / 32, PC_DIM / 64, N_ROUTES), 256, 0, stream>>>(w, wt);
    const int n8 = BATCH * ROW_IN / 8;
    conv_pose<<<(n8 + 255) / 256, 256, 0, stream>>>(pose, poseb, n8);

    for (int b0 = 0; b0 < BATCH; b0 += chunk) {
        int rows = BATCH - b0 < chunk ? BATCH - b0 : chunk;
        int nRowTiles = (rows + 127) / 128;
        vote_gemm_mfma<<<nRowTiles * 175, 256, 0, stream>>>(
            poseb + (size_t)b0 * ROW_IN, wt, voteh, rows);
        routing_kernel<<<rows, 448, 0, stream>>>(
            voteh,
            act + (size_t)b0 * N_ROUTES,
            gamma, beta, emb, bias,
            out_logits + (size_t)b0 * KCLS,
            out_act    + (size_t)b0 * N_ROUTES,
            out_coef   + (size_t)b0 * N_ROUTES * KCLS);
    }
}

// Round 5
// 321.860 us; speedup vs baseline: 1.1030x; 1.0425x over previous
//
#include <hip/hip_runtime.h>
#include <hip/hip_bf16.h>
#include <math.h>

// Problem constants
#define N_ROUTES 7
#define PC_DIM   512
#define MC_DIM   128
#define KCLS     25
#define BATCH    4096

#define ROW_IN   (N_ROUTES * PC_DIM)          // 3584 elems per batch row of pose
#define JDIM     (KCLS * MC_DIM)              // 3200 vote cols per route
#define VOTE_B   (N_ROUTES * JDIM)            // 22400 vote elems per batch elem

typedef __attribute__((ext_vector_type(8))) _Float16 half8;
typedef __attribute__((ext_vector_type(4))) float f32x4;

__device__ inline ushort f2h(float f) {
    _Float16 h = (_Float16)f;
    return __builtin_bit_cast(ushort, h);
}

__device__ inline float2 h2f2(uint u) {
    union { uint x; _Float16 h[2]; } c; c.x = u;
    return make_float2((float)c.h[0], (float)c.h[1]);
}

__device__ inline void load_lds16(const void* g, void* l) {
    __builtin_amdgcn_global_load_lds(
        (const __attribute__((address_space(1))) void*)g,
        (__attribute__((address_space(3))) void*)l, 16, 0, 0);
}

// ---------------- conversion kernels ----------------
__global__ __launch_bounds__(256) void conv_pose(const float* __restrict__ p,
                                                 ushort* __restrict__ pb, int n8) {
    int i = blockIdx.x * 256 + threadIdx.x;
    if (i >= n8) return;
    const float4* s = (const float4*)p + (size_t)i * 2;
    float4 a = s[0], b = s[1];
    ushort t[8];
    t[0]=f2h(a.x); t[1]=f2h(a.y); t[2]=f2h(a.z); t[3]=f2h(a.w);
    t[4]=f2h(b.x); t[5]=f2h(b.y); t[6]=f2h(b.z); t[7]=f2h(b.w);
    *(uint4*)(pb + (size_t)i * 8) = *(uint4*)t;
}

// w fp32 [7][512][3200] -> wt fp16 [7][3200][512] (transposed per route).
// 32j x 64d tile; each output j-row written as a FULL 128B line (8 thr x uint4).
// LDS stride 65 floats keeps both phases conflict-free.
__global__ __launch_bounds__(256) void conv_w(const float* __restrict__ w,
                                              ushort* __restrict__ wt) {
    __shared__ float t[32][65];
    const int j0 = blockIdx.x * 32, d0 = blockIdx.y * 64, r = blockIdx.z;
    const int jc = threadIdx.x & 31, dr0 = threadIdx.x >> 5;   // 8 d-rows/pass
    const float* wp = w + (size_t)r * PC_DIM * JDIM;
#pragma unroll
    for (int i = 0; i < 8; i++)
        t[jc][dr0 + i * 8] = wp[(size_t)(d0 + dr0 + i * 8) * JDIM + j0 + jc];
    __syncthreads();
    const int jr = threadIdx.x >> 3, dc = (threadIdx.x & 7) * 8;
    ushort o[8];
#pragma unroll
    for (int k = 0; k < 8; k++) o[k] = f2h(t[jr][dc + k]);
    ushort* op = wt + (size_t)r * JDIM * PC_DIM;
    *(uint4*)(op + (size_t)(j0 + jr) * PC_DIM + d0 + dc) = *(uint4*)o;
}

// ---------------- Kernel 1: MFMA vote GEMM (fp16 in, fp16 out) ----------------
// r11 (resubmit after infra failure): LDS-intensity fix. Wave tile 128x64
// (was 64x64): 12 ds_read_b128 per 32 MFMA (ratio 0.375 vs 0.5) -- the 64x64
// shape's LDS pipe demand (384cyc reads vs 310cyc MFMA per block-tile) was the
// structural ceiling (~60% max MfmaUtil; observed 30%). Block 256x128, 4 waves
// (2Mx2N), BK=32, acc[8][4]. 3-deep rotation (A 16KB + B 8KB = 24KB/buf, 72KB
// total) -> 2 blocks/CU. Counted vmcnt: stage t+2 at top of tile t (6 loads/
// thread), wait vmcnt(6) at tile end -- never 0 in steady state. setprio(1)
// around the 32-MFMA cluster. XOR swizzle (verified, 0 conflicts): chunk
// c ^ ((row>>1)&3), linear LDS dest + pre-swizzled global source.
// XCD map: grid 2800 = 8 XCDs x 350; per XCD 14 contiguous (route,rowTile)
// codes, jTile inner -> per-XCD B working set ~ one route panel (3.27MB ~ L2).

#define BAR() do { __builtin_amdgcn_sched_barrier(0); \
                   __builtin_amdgcn_s_barrier(); \
                   __builtin_amdgcn_sched_barrier(0); } while (0)
#define WAIT_LGKM0() do { asm volatile("s_waitcnt lgkmcnt(0)" ::: "memory"); \
                          __builtin_amdgcn_sched_barrier(0); } while (0)
#define WAIT_VM(n) do { asm volatile("s_waitcnt vmcnt(" #n ")" ::: "memory"); } while (0)

__global__ __launch_bounds__(256, 2) void vote_gemm_mfma(
        const ushort* __restrict__ poseb,  // [rows][3584] fp16
        const ushort* __restrict__ wt,     // [7][3200][512] fp16
        ushort* __restrict__ vote,         // [rows][7][3200] fp16
        int rows) {
    __shared__ __align__(16) char smem[73728];   // 3 bufs x (A 16KB | B 8KB)

    int route, rowTile, jTile;
    {
        const int blk = blockIdx.x;
        if (gridDim.x == 2800) {           // full batch: 16 rowTiles x 7 x 25
            const int x = blk & 7;         // XCD id (perf heuristic only)
            const int g = blk >> 3;        // 0..349
            const int q = g / 25;          // 0..13
            jTile = g - q * 25;
            const int p = x * 14 + q;      // 0..111 = route*16 + rowTile
            route = p >> 4;
            rowTile = p & 15;
        } else {
            rowTile = blk / 175;
            const int rem = blk - rowTile * 175;
            route = rem / 25;
            jTile = rem - route * 25;
        }
    }
    const int b0 = rowTile * 256;
    const int j0 = jTile * 128;

    const int tid = threadIdx.x;
    const int l = tid & 63, w = tid >> 6;
    const int wm = w >> 1, wn = w & 1;     // 2 M-waves x 2 N-waves
    const int lm = l & 15, q4 = l >> 4;
    const int xr = (l >> 1) & 3;           // == ((row>>1)&3) for row = 16k + lm

    const ushort* Aptr = poseb + (size_t)route * PC_DIM;
    const ushort* Bptr = wt + (size_t)route * JDIM * PC_DIM;

    // Staging source offsets (elements). A: 1024 chunks of 8 fp16 (256 rows x 4);
    // B: 512 chunks (128 rows x 4). chunk f: row = f>>2, c = f&3, pre-swizzled
    // source col-group qg = c ^ ((row>>1)&3).
    uint aof[4], bof[2];
    {
#pragma unroll
        for (int i = 0; i < 4; i++) {
            const int f = tid + i * 256;
            const int row = f >> 2, c = f & 3;
            const int qg = c ^ ((row >> 1) & 3);
            int ga = b0 + row; if (ga >= rows) ga = rows - 1;
            aof[i] = (uint)ga * ROW_IN + qg * 8;
        }
#pragma unroll
        for (int i = 0; i < 2; i++) {
            const int f = tid + i * 256;
            const int row = f >> 2, c = f & 3;
            const int qg = c ^ ((row >> 1) & 3);
            bof[i] = (uint)(j0 + row) * PC_DIM + qg * 8;   // j0+row <= 3199 always
        }
    }

    // LDS byte offsets of this lane's fragments (swizzled read side).
    // A section at buf+0 (256 rows), B at buf+16384 (128 rows);
    // row addr = (row*4 + pos)*16.
    const int aBase = ((wm * 128 + lm) * 4 + (q4 ^ xr)) * 16;            // + mt*1024
    const int bBase = 16384 + ((wn * 64 + lm) * 4 + (q4 ^ xr)) * 16;     // + nt*1024

    f32x4 acc[8][4] = {};

#define STAGE(kt) do { \
        char* d_ = smem + (((kt) % 3) * 24576); \
        load_lds16(Aptr + aof[0] + (kt) * 32, d_ + (size_t)tid * 16); \
        load_lds16(Aptr + aof[1] + (kt) * 32, d_ + (size_t)(tid + 256) * 16); \
        load_lds16(Aptr + aof[2] + (kt) * 32, d_ + (size_t)(tid + 512) * 16); \
        load_lds16(Aptr + aof[3] + (kt) * 32, d_ + (size_t)(tid + 768) * 16); \
        load_lds16(Bptr + bof[0] + (kt) * 32, d_ + 16384 + (size_t)tid * 16); \
        load_lds16(Bptr + bof[1] + (kt) * 32, d_ + 16384 + (size_t)(tid + 256) * 16); \
    } while (0)

    // Prologue: tiles 0,1 staged (12 loads/thread); wait tile0 (leave 6).
    STAGE(0); STAGE(1);
    WAIT_VM(6);
    BAR();

    half8 af[8], bf[4];

#pragma unroll
    for (int t = 0; t < 16; ++t) {
        if (t < 14) STAGE(t + 2);          // issue-early: loads in flight across tile
        const char* bp_ = smem + ((t % 3) * 24576);
#pragma unroll
        for (int nt = 0; nt < 4; nt++)
            bf[nt] = *(const half8*)(bp_ + bBase + nt * 1024);
#pragma unroll
        for (int mt = 0; mt < 8; mt++)
            af[mt] = *(const half8*)(bp_ + aBase + mt * 1024);
        WAIT_LGKM0();
        __builtin_amdgcn_s_setprio(1);
#pragma unroll
        for (int mt = 0; mt < 8; mt++)
#pragma unroll
            for (int nt = 0; nt < 4; nt++)
                acc[mt][nt] = __builtin_amdgcn_mfma_f32_16x16x32_f16(
                    af[mt], bf[nt], acc[mt][nt], 0, 0, 0);
        __builtin_amdgcn_s_setprio(0);
        if (t < 14)       WAIT_VM(6);      // tile t+1 landed; t+2 still in flight
        else if (t == 14) WAIT_VM(0);      // drain: tile 15 landed
        BAR();                             // also protects epilogue smem reuse (t=15)
    }

    // Epilogue: per-wave LDS transpose (wave-private 16x68 region, lgkm-fenced).
    float* ep = (float*)smem + w * 1088;   // 16*68 floats per wave (4x1088 = 17.4KB)
    const int erow = l >> 2, ec0 = (l & 3) * 16;
#pragma unroll
    for (int mt = 0; mt < 8; mt++) {
#pragma unroll
        for (int nt = 0; nt < 4; nt++)
#pragma unroll
            for (int i = 0; i < 4; i++)
                ep[(q4 * 4 + i) * 68 + nt * 16 + lm] = acc[mt][nt][i];
        asm volatile("s_waitcnt lgkmcnt(0)" ::: "memory");
        const int grow = b0 + wm * 128 + mt * 16 + erow;
        if (grow < rows) {
            ushort t16[16];
#pragma unroll
            for (int t8 = 0; t8 < 4; t8++) {
                float4 v = *(float4*)&ep[erow * 68 + ec0 + t8 * 4];
                t16[t8*4+0]=f2h(v.x); t16[t8*4+1]=f2h(v.y);
                t16[t8*4+2]=f2h(v.z); t16[t8*4+3]=f2h(v.w);
            }
            ushort* dst = vote + (size_t)grow * VOTE_B + route * JDIM + j0 + wn * 64 + ec0;
            ((uint4*)dst)[0] = ((uint4*)t16)[0];
            ((uint4*)dst)[1] = ((uint4*)t16)[1];
        }
        asm volatile("s_waitcnt lgkmcnt(0)" ::: "memory");
    }
}

// ---------------- Kernel 2: fused routing ----------------
// Block = one batch elem, 448 threads (7 waves). Lane decomposition:
//   sub = l&15 -> v-dims [8*sub, 8*sub+8);  mg = l>>4;  m = wv + 7*mg (28 slots, 25 valid).
// Votes unpacked ONCE to 56 fp32 regs. Reductions: 4-step shfl over 16 lanes.
__global__ __launch_bounds__(448) void routing_kernel(
        const ushort* __restrict__ vote16,  // [chunk][7][25][128] fp16
        const float* __restrict__ act,      // (pre-offset)
        const float* __restrict__ gamma,
        const float* __restrict__ beta,
        const float* __restrict__ emb,      // [25,128]
        const float* __restrict__ bias,     // [25]
        float* __restrict__ out_logits,
        float* __restrict__ out_act,
        float* __restrict__ out_coef) {
    const int b = blockIdx.x;
    __shared__ float coef_s[N_ROUTES * KCLS];
    __shared__ float act_s[8];

    const int tid = threadIdx.x, l = tid & 63, wv = tid >> 6;   // 7 waves
    const int sub = l & 15, mg = l >> 4;
    const int m = wv + 7 * mg;                // 0..27
    const bool mv = (m < KCLS);

    if (tid < N_ROUTES) {
        float a = act[(size_t)b * N_ROUTES + tid];
        act_s[tid] = a;
        out_act[(size_t)b * N_ROUTES + tid] = a;
    }

    // Load votes (coalesced 16B) and unpack to fp32 ONCE.
    float vf[N_ROUTES][8];
    if (mv) {
        const uint4* vb = (const uint4*)(vote16 + (size_t)b * VOTE_B);  // n*400 + m*16 + sub
#pragma unroll
        for (int n = 0; n < N_ROUTES; n++) {
            uint4 q = vb[n * 400 + m * 16 + sub];
            float2 f0 = h2f2(q.x), f1 = h2f2(q.y), f2 = h2f2(q.z), f3 = h2f2(q.w);
            vf[n][0] = f0.x; vf[n][1] = f0.y; vf[n][2] = f1.x; vf[n][3] = f1.y;
            vf[n][4] = f2.x; vf[n][5] = f2.y; vf[n][6] = f3.x; vf[n][7] = f3.y;
        }
    } else {
#pragma unroll
        for (int n = 0; n < N_ROUTES; n++)
#pragma unroll
            for (int j = 0; j < 8; j++) vf[n][j] = 0.f;
    }
    const int mc = mv ? m : 24;

    float g[8], be[8];
    *(float4*)(g)      = *(const float4*)(gamma + 8 * sub);
    *(float4*)(g + 4)  = *(const float4*)(gamma + 8 * sub + 4);
    *(float4*)(be)     = *(const float4*)(beta  + 8 * sub);
    *(float4*)(be + 4) = *(const float4*)(beta  + 8 * sub + 4);
    __syncthreads();   // act_s ready

    const float scale = 0.088388347648318447f;    // 1/sqrt(128)
    float pose[8];

    auto update = [&](bool first) {
        float r[8];
#pragma unroll
        for (int j = 0; j < 8; j++) r[j] = 0.f;
#pragma unroll
        for (int n = 0; n < N_ROUTES; n++) {
            float c = first ? (act_s[n] * 0.04f) : (coef_s[n * KCLS + mc] * act_s[n]);
#pragma unroll
            for (int j = 0; j < 8; j++) r[j] += c * vf[n][j];
        }
        float S = 0.f, Q = 0.f;
#pragma unroll
        for (int j = 0; j < 8; j++) { S += r[j]; Q += r[j] * r[j]; }
#pragma unroll
        for (int o = 8; o; o >>= 1) {
            S += __shfl_xor(S, o);
            Q += __shfl_xor(Q, o);
        }
        float mean = S * 0.0078125f;
        float var  = Q * 0.0078125f - mean * mean;
        float rs   = rsqrtf(var + 1e-5f);
#pragma unroll
        for (int j = 0; j < 8; j++) pose[j] = (r[j] - mean) * rs * g[j] + be[j];
    };

    update(true);
    __syncthreads();

    const int sgrp = tid >> 5, slane = tid & 31;   // 14 x 32-lane groups for softmax

    for (int it = 1; it < 3; it++) {
        // agreement: d[n] = <vote[n][m], pose[m]>
        float d[N_ROUTES];
#pragma unroll
        for (int n = 0; n < N_ROUTES; n++) {
            float t = 0.f;
#pragma unroll
            for (int j = 0; j < 8; j++) t += vf[n][j] * pose[j];
            d[n] = t;
        }
#pragma unroll
        for (int o = 8; o; o >>= 1)
#pragma unroll
            for (int n = 0; n < N_ROUTES; n++) d[n] += __shfl_xor(d[n], o);
        if (sub == 0 && mv) {
#pragma unroll
            for (int n = 0; n < N_ROUTES; n++) coef_s[n * KCLS + m] = d[n] * scale;
        }
        __syncthreads();
        // parallel softmax: group sgrp = route, lane slane = m
        if (sgrp < N_ROUTES) {
            float c = (slane < KCLS) ? coef_s[sgrp * KCLS + slane] : -1e30f;
            float mx = c;
#pragma unroll
            for (int o = 16; o; o >>= 1) mx = fmaxf(mx, __shfl_xor(mx, o, 32));
            float e = (slane < KCLS) ? expf(c - mx) : 0.f;
            float s = e;
#pragma unroll
            for (int o = 16; o; o >>= 1) s += __shfl_xor(s, o, 32);
            if (slane < KCLS) coef_s[sgrp * KCLS + slane] = e / s;
        }
        __syncthreads();
        update(false);
        if (it == 1) __syncthreads();   // coef_s reads done before next agree overwrites
    }

    // logits
    float e[8];
    *(float4*)(e)     = *(const float4*)(emb + mc * MC_DIM + 8 * sub);
    *(float4*)(e + 4) = *(const float4*)(emb + mc * MC_DIM + 8 * sub + 4);
    float dd = 0.f;
#pragma unroll
    for (int j = 0; j < 8; j++) dd += pose[j] * e[j];
#pragma unroll
    for (int o = 8; o; o >>= 1) dd += __shfl_xor(dd, o);
    if (sub == 0 && mv) out_logits[(size_t)b * KCLS + m] = dd + bias[m];

    if (tid < N_ROUTES * KCLS)
        out_coef[(size_t)b * (N_ROUTES * KCLS) + tid] = coef_s[tid];
}

// ---------------- launch ----------------
extern "C" void kernel_launch(void* const* d_in, const int* in_sizes, int n_in,
                              void* d_out, int out_size, void* d_ws, size_t ws_size,
                              hipStream_t stream) {
    const float* pose  = (const float*)d_in[0];
    const float* act   = (const float*)d_in[1];
    const float* w     = (const float*)d_in[2];
    const float* gamma = (const float*)d_in[3];
    const float* beta  = (const float*)d_in[4];
    const float* emb   = (const float*)d_in[5];
    const float* bias  = (const float*)d_in[6];

    float* out        = (float*)d_out;
    float* out_logits = out;
    float* out_act    = out + BATCH * KCLS;
    float* out_coef   = out + BATCH * KCLS + BATCH * N_ROUTES;

    // workspace: wt fp16 | poseb fp16 | vote fp16 (chunked)
    const size_t wt_bytes    = (size_t)N_ROUTES * JDIM * PC_DIM * 2;
    const size_t poseb_bytes = (size_t)BATCH * ROW_IN * 2;
    ushort* wt    = (ushort*)d_ws;
    ushort* poseb = (ushort*)((char*)d_ws + wt_bytes);
    ushort* voteh = (ushort*)((char*)d_ws + wt_bytes + poseb_bytes);

    size_t rem = ws_size > wt_bytes + poseb_bytes ? ws_size - wt_bytes - poseb_bytes : 0;
    size_t cap = rem / ((size_t)VOTE_B * 2);
    int chunk;
    if (cap >= (size_t)BATCH)  chunk = BATCH;   // single dispatch: deepest grid, no tail split
    else if (cap >= 256)       chunk = (int)(cap & ~(size_t)255);
    else                       chunk = (int)(cap > 0 ? cap : 1);

    conv_w<<<dim3(JDIM / 32, PC_DIM / 64, N_ROUTES), 256, 0, stream>>>(w, wt);
    const int n8 = BATCH * ROW_IN / 8;
    conv_pose<<<(n8 + 255) / 256, 256, 0, stream>>>(pose, poseb, n8);

    for (int b0 = 0; b0 < BATCH; b0 += chunk) {
        int rows = BATCH - b0 < chunk ? BATCH - b0 : chunk;
        int nRowTiles = (rows + 255) / 256;
        vote_gemm_mfma<<<nRowTiles * 175, 256, 0, stream>>>(
            poseb + (size_t)b0 * ROW_IN, wt, voteh, rows);
        routing_kernel<<<rows, 448, 0, stream>>>(
            voteh,
            act + (size_t)b0 * N_ROUTES,
            gamma, beta, emb, bias,
            out_logits + (size_t)b0 * KCLS,
            out_act    + (size_t)b0 * N_ROUTES,
            out_coef   + (size_t)b0 * N_ROUTES * KCLS);
    }
}

// Round 6
// 320.044 us; speedup vs baseline: 1.1092x; 1.0057x over previous
//
#include <hip/hip_runtime.h>
#include <hip/hip_bf16.h>
#include <math.h>

// Problem constants
#define N_ROUTES 7
#define PC_DIM   512
#define MC_DIM   128
#define KCLS     25
#define BATCH    4096

#define ROW_IN   (N_ROUTES * PC_DIM)          // 3584 elems per batch row of pose
#define JDIM     (KCLS * MC_DIM)              // 3200 vote cols per route
#define VOTE_B   (N_ROUTES * JDIM)            // 22400 vote elems per batch elem

typedef __attribute__((ext_vector_type(8))) _Float16 half8;
typedef __attribute__((ext_vector_type(4))) float f32x4;

__device__ inline ushort f2h(float f) {
    _Float16 h = (_Float16)f;
    return __builtin_bit_cast(ushort, h);
}

__device__ inline float2 h2f2(uint u) {
    union { uint x; _Float16 h[2]; } c; c.x = u;
    return make_float2((float)c.h[0], (float)c.h[1]);
}

__device__ inline void load_lds16(const void* g, void* l) {
    __builtin_amdgcn_global_load_lds(
        (const __attribute__((address_space(1))) void*)g,
        (__attribute__((address_space(3))) void*)l, 16, 0, 0);
}

// ---------------- conversion kernels ----------------
__global__ __launch_bounds__(256) void conv_pose(const float* __restrict__ p,
                                                 ushort* __restrict__ pb, int n8) {
    int i = blockIdx.x * 256 + threadIdx.x;
    if (i >= n8) return;
    const float4* s = (const float4*)p + (size_t)i * 2;
    float4 a = s[0], b = s[1];
    ushort t[8];
    t[0]=f2h(a.x); t[1]=f2h(a.y); t[2]=f2h(a.z); t[3]=f2h(a.w);
    t[4]=f2h(b.x); t[5]=f2h(b.y); t[6]=f2h(b.z); t[7]=f2h(b.w);
    *(uint4*)(pb + (size_t)i * 8) = *(uint4*)t;
}

// w fp32 [7][512][3200] -> wt fp16 [7][3200][512] (transposed per route).
// 32j x 64d tile; each output j-row written as a FULL 128B line (8 thr x uint4).
// LDS stride 65 floats keeps both phases conflict-free.
__global__ __launch_bounds__(256) void conv_w(const float* __restrict__ w,
                                              ushort* __restrict__ wt) {
    __shared__ float t[32][65];
    const int j0 = blockIdx.x * 32, d0 = blockIdx.y * 64, r = blockIdx.z;
    const int jc = threadIdx.x & 31, dr0 = threadIdx.x >> 5;   // 8 d-rows/pass
    const float* wp = w + (size_t)r * PC_DIM * JDIM;
#pragma unroll
    for (int i = 0; i < 8; i++)
        t[jc][dr0 + i * 8] = wp[(size_t)(d0 + dr0 + i * 8) * JDIM + j0 + jc];
    __syncthreads();
    const int jr = threadIdx.x >> 3, dc = (threadIdx.x & 7) * 8;
    ushort o[8];
#pragma unroll
    for (int k = 0; k < 8; k++) o[k] = f2h(t[jr][dc + k]);
    ushort* op = wt + (size_t)r * JDIM * PC_DIM;
    *(uint4*)(op + (size_t)(j0 + jr) * PC_DIM + d0 + dc) = *(uint4*)o;
}

// ---------------- Kernel 1: MFMA vote GEMM (fp16 in, fp16 out) ----------------
// r12: UNPIN the intra-phase schedule. r8-r11 forced {12 ds_read -> lgkmcnt(0)
// -> sched_barrier(0) -> 32 MFMA} per K-step: the whole LDS burst had to retire
// before the first MFMA issued (MfmaUtil pinned at 28-31% across three tile
// shapes -- serialization, not pipe saturation: MFMA 45us + LDS 56us of work in
// a 131us kernel). MFMA (mt,nt) needs only af[mt],bf[nt]; the compiler emits
// fine-grained counted lgkmcnt interleave when not pinned (m97 asm; m141 shows
// pinning costs ~40%). This round: same geometry as r11 (256x128, 4 waves 2Mx2N
// wave tile 128x64, BK=32, 3-deep rotation 72KB -> 2 blocks/CU, counted
// vmcnt(6) across K-steps, XOR swizzle, FETCH-verified XCD map); the ONLY
// change is dropping lgkmcnt(0)/sched_barrier/setprio inside the phase.
// BAR()'s sched_barriers stay: they fence the LDS buffer rotation.

#define BAR() do { __builtin_amdgcn_sched_barrier(0); \
                   __builtin_amdgcn_s_barrier(); \
                   __builtin_amdgcn_sched_barrier(0); } while (0)
#define WAIT_VM(n) do { asm volatile("s_waitcnt vmcnt(" #n ")" ::: "memory"); } while (0)

__global__ __launch_bounds__(256, 2) void vote_gemm_mfma(
        const ushort* __restrict__ poseb,  // [rows][3584] fp16
        const ushort* __restrict__ wt,     // [7][3200][512] fp16
        ushort* __restrict__ vote,         // [rows][7][3200] fp16
        int rows) {
    __shared__ __align__(16) char smem[73728];   // 3 bufs x (A 16KB | B 8KB)

    int route, rowTile, jTile;
    {
        const int blk = blockIdx.x;
        if (gridDim.x == 2800) {           // full batch: 16 rowTiles x 7 x 25
            const int x = blk & 7;         // XCD id (perf heuristic only)
            const int g = blk >> 3;        // 0..349
            const int q = g / 25;          // 0..13
            jTile = g - q * 25;
            const int p = x * 14 + q;      // 0..111 = route*16 + rowTile
            route = p >> 4;
            rowTile = p & 15;
        } else {
            rowTile = blk / 175;
            const int rem = blk - rowTile * 175;
            route = rem / 25;
            jTile = rem - route * 25;
        }
    }
    const int b0 = rowTile * 256;
    const int j0 = jTile * 128;

    const int tid = threadIdx.x;
    const int l = tid & 63, w = tid >> 6;
    const int wm = w >> 1, wn = w & 1;     // 2 M-waves x 2 N-waves
    const int lm = l & 15, q4 = l >> 4;
    const int xr = (l >> 1) & 3;           // == ((row>>1)&3) for row = 16k + lm

    const ushort* Aptr = poseb + (size_t)route * PC_DIM;
    const ushort* Bptr = wt + (size_t)route * JDIM * PC_DIM;

    // Staging source offsets (elements). A: 1024 chunks of 8 fp16 (256 rows x 4);
    // B: 512 chunks (128 rows x 4). chunk f: row = f>>2, c = f&3, pre-swizzled
    // source col-group qg = c ^ ((row>>1)&3).
    uint aof[4], bof[2];
    {
#pragma unroll
        for (int i = 0; i < 4; i++) {
            const int f = tid + i * 256;
            const int row = f >> 2, c = f & 3;
            const int qg = c ^ ((row >> 1) & 3);
            int ga = b0 + row; if (ga >= rows) ga = rows - 1;
            aof[i] = (uint)ga * ROW_IN + qg * 8;
        }
#pragma unroll
        for (int i = 0; i < 2; i++) {
            const int f = tid + i * 256;
            const int row = f >> 2, c = f & 3;
            const int qg = c ^ ((row >> 1) & 3);
            bof[i] = (uint)(j0 + row) * PC_DIM + qg * 8;   // j0+row <= 3199 always
        }
    }

    // LDS byte offsets of this lane's fragments (swizzled read side).
    // A section at buf+0 (256 rows), B at buf+16384 (128 rows);
    // row addr = (row*4 + pos)*16.
    const int aBase = ((wm * 128 + lm) * 4 + (q4 ^ xr)) * 16;            // + mt*1024
    const int bBase = 16384 + ((wn * 64 + lm) * 4 + (q4 ^ xr)) * 16;     // + nt*1024

    f32x4 acc[8][4] = {};

#define STAGE(kt) do { \
        char* d_ = smem + (((kt) % 3) * 24576); \
        load_lds16(Aptr + aof[0] + (kt) * 32, d_ + (size_t)tid * 16); \
        load_lds16(Aptr + aof[1] + (kt) * 32, d_ + (size_t)(tid + 256) * 16); \
        load_lds16(Aptr + aof[2] + (kt) * 32, d_ + (size_t)(tid + 512) * 16); \
        load_lds16(Aptr + aof[3] + (kt) * 32, d_ + (size_t)(tid + 768) * 16); \
        load_lds16(Bptr + bof[0] + (kt) * 32, d_ + 16384 + (size_t)tid * 16); \
        load_lds16(Bptr + bof[1] + (kt) * 32, d_ + 16384 + (size_t)(tid + 256) * 16); \
    } while (0)

    // Prologue: tiles 0,1 staged (12 loads/thread); wait tile0 (leave 6).
    STAGE(0); STAGE(1);
    WAIT_VM(6);
    BAR();

#pragma unroll
    for (int t = 0; t < 16; ++t) {
        if (t < 14) STAGE(t + 2);          // issue-early: loads in flight across tile
        const char* bp_ = smem + ((t % 3) * 24576);
        half8 af[8], bf[4];
#pragma unroll
        for (int nt = 0; nt < 4; nt++)
            bf[nt] = *(const half8*)(bp_ + bBase + nt * 1024);
#pragma unroll
        for (int mt = 0; mt < 8; mt++)
            af[mt] = *(const half8*)(bp_ + aBase + mt * 1024);
        // NO lgkmcnt(0) / sched_barrier / setprio here: compiler interleaves
        // ds_read with MFMA under counted lgkmcnt (the r8-r11 pinning was the
        // 30%-MfmaUtil serializer).
#pragma unroll
        for (int mt = 0; mt < 8; mt++)
#pragma unroll
            for (int nt = 0; nt < 4; nt++)
                acc[mt][nt] = __builtin_amdgcn_mfma_f32_16x16x32_f16(
                    af[mt], bf[nt], acc[mt][nt], 0, 0, 0);
        if (t < 14)       WAIT_VM(6);      // tile t+1 landed; t+2 still in flight
        else if (t == 14) WAIT_VM(0);      // drain: tile 15 landed
        BAR();                             // also protects epilogue smem reuse (t=15)
    }

    // Epilogue: per-wave LDS transpose, double-buffered (two wave-private
    // 16x68 regions alternate -> no trailing wait before refilling).
    const int erow = l >> 2, ec0 = (l & 3) * 16;
#pragma unroll
    for (int mt = 0; mt < 8; mt++) {
        float* ep = (float*)smem + w * 1088 + (mt & 1) * 4352;
#pragma unroll
        for (int nt = 0; nt < 4; nt++)
#pragma unroll
            for (int i = 0; i < 4; i++)
                ep[(q4 * 4 + i) * 68 + nt * 16 + lm] = acc[mt][nt][i];
        asm volatile("s_waitcnt lgkmcnt(0)" ::: "memory");
        const int grow = b0 + wm * 128 + mt * 16 + erow;
        if (grow < rows) {
            ushort t16[16];
#pragma unroll
            for (int t8 = 0; t8 < 4; t8++) {
                float4 v = *(float4*)&ep[erow * 68 + ec0 + t8 * 4];
                t16[t8*4+0]=f2h(v.x); t16[t8*4+1]=f2h(v.y);
                t16[t8*4+2]=f2h(v.z); t16[t8*4+3]=f2h(v.w);
            }
            ushort* dst = vote + (size_t)grow * VOTE_B + route * JDIM + j0 + wn * 64 + ec0;
            ((uint4*)dst)[0] = ((uint4*)t16)[0];
            ((uint4*)dst)[1] = ((uint4*)t16)[1];
        }
    }
}

// ---------------- Kernel 2: fused routing ----------------
// Block = one batch elem, 448 threads (7 waves). Lane decomposition:
//   sub = l&15 -> v-dims [8*sub, 8*sub+8);  mg = l>>4;  m = wv + 7*mg (28 slots, 25 valid).
// Votes unpacked ONCE to 56 fp32 regs. Reductions: 4-step shfl over 16 lanes.
__global__ __launch_bounds__(448) void routing_kernel(
        const ushort* __restrict__ vote16,  // [chunk][7][25][128] fp16
        const float* __restrict__ act,      // (pre-offset)
        const float* __restrict__ gamma,
        const float* __restrict__ beta,
        const float* __restrict__ emb,      // [25,128]
        const float* __restrict__ bias,     // [25]
        float* __restrict__ out_logits,
        float* __restrict__ out_act,
        float* __restrict__ out_coef) {
    const int b = blockIdx.x;
    __shared__ float coef_s[N_ROUTES * KCLS];
    __shared__ float act_s[8];

    const int tid = threadIdx.x, l = tid & 63, wv = tid >> 6;   // 7 waves
    const int sub = l & 15, mg = l >> 4;
    const int m = wv + 7 * mg;                // 0..27
    const bool mv = (m < KCLS);

    if (tid < N_ROUTES) {
        float a = act[(size_t)b * N_ROUTES + tid];
        act_s[tid] = a;
        out_act[(size_t)b * N_ROUTES + tid] = a;
    }

    // Load votes (coalesced 16B) and unpack to fp32 ONCE.
    float vf[N_ROUTES][8];
    if (mv) {
        const uint4* vb = (const uint4*)(vote16 + (size_t)b * VOTE_B);  // n*400 + m*16 + sub
#pragma unroll
        for (int n = 0; n < N_ROUTES; n++) {
            uint4 q = vb[n * 400 + m * 16 + sub];
            float2 f0 = h2f2(q.x), f1 = h2f2(q.y), f2 = h2f2(q.z), f3 = h2f2(q.w);
            vf[n][0] = f0.x; vf[n][1] = f0.y; vf[n][2] = f1.x; vf[n][3] = f1.y;
            vf[n][4] = f2.x; vf[n][5] = f2.y; vf[n][6] = f3.x; vf[n][7] = f3.y;
        }
    } else {
#pragma unroll
        for (int n = 0; n < N_ROUTES; n++)
#pragma unroll
            for (int j = 0; j < 8; j++) vf[n][j] = 0.f;
    }
    const int mc = mv ? m : 24;

    float g[8], be[8];
    *(float4*)(g)      = *(const float4*)(gamma + 8 * sub);
    *(float4*)(g + 4)  = *(const float4*)(gamma + 8 * sub + 4);
    *(float4*)(be)     = *(const float4*)(beta  + 8 * sub);
    *(float4*)(be + 4) = *(const float4*)(beta  + 8 * sub + 4);
    __syncthreads();   // act_s ready

    const float scale = 0.088388347648318447f;    // 1/sqrt(128)
    float pose[8];

    auto update = [&](bool first) {
        float r[8];
#pragma unroll
        for (int j = 0; j < 8; j++) r[j] = 0.f;
#pragma unroll
        for (int n = 0; n < N_ROUTES; n++) {
            float c = first ? (act_s[n] * 0.04f) : (coef_s[n * KCLS + mc] * act_s[n]);
#pragma unroll
            for (int j = 0; j < 8; j++) r[j] += c * vf[n][j];
        }
        float S = 0.f, Q = 0.f;
#pragma unroll
        for (int j = 0; j < 8; j++) { S += r[j]; Q += r[j] * r[j]; }
#pragma unroll
        for (int o = 8; o; o >>= 1) {
            S += __shfl_xor(S, o);
            Q += __shfl_xor(Q, o);
        }
        float mean = S * 0.0078125f;
        float var  = Q * 0.0078125f - mean * mean;
        float rs   = rsqrtf(var + 1e-5f);
#pragma unroll
        for (int j = 0; j < 8; j++) pose[j] = (r[j] - mean) * rs * g[j] + be[j];
    };

    update(true);
    __syncthreads();

    const int sgrp = tid >> 5, slane = tid & 31;   // 14 x 32-lane groups for softmax

    for (int it = 1; it < 3; it++) {
        // agreement: d[n] = <vote[n][m], pose[m]>
        float d[N_ROUTES];
#pragma unroll
        for (int n = 0; n < N_ROUTES; n++) {
            float t = 0.f;
#pragma unroll
            for (int j = 0; j < 8; j++) t += vf[n][j] * pose[j];
            d[n] = t;
        }
#pragma unroll
        for (int o = 8; o; o >>= 1)
#pragma unroll
            for (int n = 0; n < N_ROUTES; n++) d[n] += __shfl_xor(d[n], o);
        if (sub == 0 && mv) {
#pragma unroll
            for (int n = 0; n < N_ROUTES; n++) coef_s[n * KCLS + m] = d[n] * scale;
        }
        __syncthreads();
        // parallel softmax: group sgrp = route, lane slane = m
        if (sgrp < N_ROUTES) {
            float c = (slane < KCLS) ? coef_s[sgrp * KCLS + slane] : -1e30f;
            float mx = c;
#pragma unroll
            for (int o = 16; o; o >>= 1) mx = fmaxf(mx, __shfl_xor(mx, o, 32));
            float e = (slane < KCLS) ? expf(c - mx) : 0.f;
            float s = e;
#pragma unroll
            for (int o = 16; o; o >>= 1) s += __shfl_xor(s, o, 32);
            if (slane < KCLS) coef_s[sgrp * KCLS + slane] = e / s;
        }
        __syncthreads();
        update(false);
        if (it == 1) __syncthreads();   // coef_s reads done before next agree overwrites
    }

    // logits
    float e[8];
    *(float4*)(e)     = *(const float4*)(emb + mc * MC_DIM + 8 * sub);
    *(float4*)(e + 4) = *(const float4*)(emb + mc * MC_DIM + 8 * sub + 4);
    float dd = 0.f;
#pragma unroll
    for (int j = 0; j < 8; j++) dd += pose[j] * e[j];
#pragma unroll
    for (int o = 8; o; o >>= 1) dd += __shfl_xor(dd, o);
    if (sub == 0 && mv) out_logits[(size_t)b * KCLS + m] = dd + bias[m];

    if (tid < N_ROUTES * KCLS)
        out_coef[(size_t)b * (N_ROUTES * KCLS) + tid] = coef_s[tid];
}

// ---------------- launch ----------------
extern "C" void kernel_launch(void* const* d_in, const int* in_sizes, int n_in,
                              void* d_out, int out_size, void* d_ws, size_t ws_size,
                              hipStream_t stream) {
    const float* pose  = (const float*)d_in[0];
    const float* act   = (const float*)d_in[1];
    const float* w     = (const float*)d_in[2];
    const float* gamma = (const float*)d_in[3];
    const float* beta  = (const float*)d_in[4];
    const float* emb   = (const float*)d_in[5];
    const float* bias  = (const float*)d_in[6];

    float* out        = (float*)d_out;
    float* out_logits = out;
    float* out_act    = out + BATCH * KCLS;
    float* out_coef   = out + BATCH * KCLS + BATCH * N_ROUTES;

    // workspace: wt fp16 | poseb fp16 | vote fp16 (chunked)
    const size_t wt_bytes    = (size_t)N_ROUTES * JDIM * PC_DIM * 2;
    const size_t poseb_bytes = (size_t)BATCH * ROW_IN * 2;
    ushort* wt    = (ushort*)d_ws;
    ushort* poseb = (ushort*)((char*)d_ws + wt_bytes);
    ushort* voteh = (ushort*)((char*)d_ws + wt_bytes + poseb_bytes);

    size_t rem = ws_size > wt_bytes + poseb_bytes ? ws_size - wt_bytes - poseb_bytes : 0;
    size_t cap = rem / ((size_t)VOTE_B * 2);
    int chunk;
    if (cap >= (size_t)BATCH)  chunk = BATCH;   // single dispatch: deepest grid, no tail split
    else if (cap >= 256)       chunk = (int)(cap & ~(size_t)255);
    else                       chunk = (int)(cap > 0 ? cap : 1);

    conv_w<<<dim3(JDIM / 32, PC_DIM / 64, N_ROUTES), 256, 0, stream>>>(w, wt);
    const int n8 = BATCH * ROW_IN / 8;
    conv_pose<<<(n8 + 255) / 256, 256, 0, stream>>>(pose, poseb, n8);

    for (int b0 = 0; b0 < BATCH; b0 += chunk) {
        int rows = BATCH - b0 < chunk ? BATCH - b0 : chunk;
        int nRowTiles = (rows + 255) / 256;
        vote_gemm_mfma<<<nRowTiles * 175, 256, 0, stream>>>(
            poseb + (size_t)b0 * ROW_IN, wt, voteh, rows);
        routing_kernel<<<rows, 448, 0, stream>>>(
            voteh,
            act + (size_t)b0 * N_ROUTES,
            gamma, beta, emb, bias,
            out_logits + (size_t)b0 * KCLS,
            out_act    + (size_t)b0 * N_ROUTES,
            out_coef   + (size_t)b0 * N_ROUTES * KCLS);
    }
}